// Round 6
// baseline (16707.867 us; speedup 1.0000x reference)
//
#include <hip/hip_runtime.h>
#include <hip/hip_bf16.h>
#include <math.h>

// UHG InfoNCE: fused distance/similarity matrix + streaming row-logsumexp.
// N=8192, D=64 fp32. Mandatory writes ~537MB -> ~86us floor.
// r4: 512 blocks, bit-exact (absmax=0.0), main ~300us (2 blocks/CU, stall-bound).
// r5: FAILED absmax=ln2 — grid covered only cols 0..4095 (4 quarters x 1024).
// r6 fix: 8 column-slices x 1024 cols, grid 4096 = 512 rowblocks x 8 slices.
//
// Analytic simplifications (exact in fp32, proven absmax=0.0 in r4):
//  1. pos_sim cancels: per_row = -sims[i,0] + logsumexp_j(sims[i,j]).
//  2. max(ratio, 1.0+1e-9) == max(ratio, 1.0f) in fp32; ratio<1 for ~all
//     pairs -> dist=0, sim=0 exactly. Classify by inner^2 > 0.9999*denom2;
//     borderline lanes take the exact div/clamp path.
//  3. Row max is exactly 0 -> accumulate S = sum(exp(sim)) with m=0 fixed.

#define NN 8192
#define DD 64

static constexpr float EPSV      = 1e-9f;
static constexpr float NEG_INV_T = -1.0f / 0.07f;

typedef const __attribute__((address_space(1))) unsigned int* gas_u32p;
typedef __attribute__((address_space(3))) unsigned int* las_u32p;

__device__ __forceinline__ void load_lds16(const void* g, void* l) {
    __builtin_amdgcn_global_load_lds((gas_u32p)g, (las_u32p)l, 16, 0, 0);
}

// ---------------------------------------------------------------------------
// Kernel 1: Kt[d][j] = K[j][d], d==63 (timelike) negated.
// ---------------------------------------------------------------------------
__global__ __launch_bounds__(256) void uhg_transpose_negate(
    const float* __restrict__ K, float* __restrict__ Kt)
{
    __shared__ float T[64][65];
    const int tid = threadIdx.x;
    const int j0  = blockIdx.x * 64;
    {
        const int j = tid >> 2;
        const int c = (tid & 3) * 16;
        const float* src = K + (size_t)(j0 + j) * DD + c;
        #pragma unroll
        for (int u = 0; u < 4; ++u) {
            const float4 v = *reinterpret_cast<const float4*>(src + 4 * u);
            T[j][c + 4*u + 0] = v.x;
            T[j][c + 4*u + 1] = v.y;
            T[j][c + 4*u + 2] = v.z;
            T[j][c + 4*u + 3] = v.w;
        }
    }
    __syncthreads();
    {
        const int d = tid >> 2;
        const int c = (tid & 3) * 16;
        const float sgn = (d == 63) ? -1.0f : 1.0f;
        float* dst = Kt + (size_t)d * NN + j0 + c;
        #pragma unroll
        for (int u = 0; u < 4; ++u) {
            float4 v;
            v.x = sgn * T[c + 4*u + 0][d];
            v.y = sgn * T[c + 4*u + 1][d];
            v.z = sgn * T[c + 4*u + 2][d];
            v.w = sgn * T[c + 4*u + 3][d];
            *reinterpret_cast<float4*>(dst + 4 * u) = v;
        }
    }
}

// ---------------------------------------------------------------------------
// Kernel 2: Minkowski self-inner products qq[i], kk[j].
// ---------------------------------------------------------------------------
__global__ __launch_bounds__(256) void uhg_qqkk(
    const float* __restrict__ Q, const float* __restrict__ K,
    float* __restrict__ qq, float* __restrict__ kk)
{
    const int i = blockIdx.x * 256 + threadIdx.x;
    const bool isQ = (i < NN);
    const int r = isQ ? i : (i - NN);
    const float* src = (isQ ? Q : K) + (size_t)r * DD;
    float acc = 0.0f;
    #pragma unroll
    for (int c = 0; c < 15; ++c) {
        const float4 v = *reinterpret_cast<const float4*>(src + 4 * c);
        acc += v.x*v.x + v.y*v.y + v.z*v.z + v.w*v.w;
    }
    const float4 v = *reinterpret_cast<const float4*>(src + 60);
    acc += v.x*v.x + v.y*v.y + v.z*v.z;
    acc -= v.w*v.w;
    (isQ ? qq : kk)[r] = acc;
}

// ---------------------------------------------------------------------------
// Kernel 3: main fused kernel.
// Grid 4096 x 256 thr. Block (rblk, cs) owns rows [16*rblk,+16) x cols
// [1024*cs,+1024), cs in 0..7. 4 tiles of 256 cols; K staged in 16-dim
// chunks via global_load_lds (Ks 16.6KB + Qs 5.1KB = 21.8KB -> 4 blocks/CU).
// Thread: 4 rows x 4 strided cols. Bit-exact epilogue (r4-verified).
// ---------------------------------------------------------------------------
__global__ __launch_bounds__(256, 4) void uhg_main(
    const float* __restrict__ Q, const float* __restrict__ Kt,
    const float* __restrict__ qq, const float* __restrict__ kk,
    float* __restrict__ out_sims, float* __restrict__ out_dist,
    float* __restrict__ Spart, float* __restrict__ sim0part)
{
    constexpr int TM  = 16;    // rows per block
    constexpr int CB  = 1024;  // cols per block
    constexpr int TN  = 256;   // cols per tile
    constexpr int DCH = 16;    // dims per K chunk

    __shared__ float Qs[DD][20];      // dim-major Q tile (pad 20)
    __shared__ float Ks[DCH][260];    // dim-major K chunk (pad 260, 16B rows)

    const int tid   = threadIdx.x;
    const int tx    = tid & 63;
    const int ty    = tid >> 6;       // wave id (uniform)
    const int cs    = blockIdx.x & 7; // column slice (8 x 1024 = full N)
    const int row0  = (blockIdx.x >> 3) * TM;
    const int cbase = cs * CB;
    const int wrow  = 4 * ty;

    // ---- stage Q tile (once): 16 rows x 64 dims, dim-major ----
    {
        const int r  = tid >> 4;      // 0..15
        const int dc = (tid & 15) * 4;
        const float4 v = *reinterpret_cast<const float4*>(
            Q + (size_t)(row0 + r) * DD + dc);
        Qs[dc + 0][r] = v.x;
        Qs[dc + 1][r] = v.y;
        Qs[dc + 2][r] = v.z;
        Qs[dc + 3][r] = v.w;
    }

    const float4 rq4 = *reinterpret_cast<const float4*>(qq + row0 + wrow);
    const float rq[4] = {rq4.x, rq4.y, rq4.z, rq4.w};

    float s[4]     = {0, 0, 0, 0};    // S = sum(exp(sim)), m fixed at 0
    float sim0r[4] = {0, 0, 0, 0};

    // per-row output bases; in-block offsets fit 13-bit store immediates
    float* ps[4];
    float* pd[4];
    #pragma unroll
    for (int rr = 0; rr < 4; ++rr) {
        const size_t rowoff = (size_t)(row0 + wrow + rr) * NN + cbase + tx;
        ps[rr] = out_sims + rowoff;
        pd[rr] = out_dist + rowoff;
    }

    for (int t = 0; t < CB / TN; ++t) {
        const int c0 = cbase + t * TN;
        float acc[4][4] = {};

        #pragma unroll
        for (int ch = 0; ch < DD / DCH; ++ch) {
            const int dbase = ch * DCH;
            __syncthreads();          // Ks free (prev readers done)
            {
                const int j = 4 * ty; // wave stages 4 dim-rows (1KB each)
                #pragma unroll
                for (int u = 0; u < 4; ++u)
                    load_lds16(Kt + (size_t)(dbase + j + u) * NN + c0 + 4 * tx,
                               &Ks[j + u][0]);
            }
            __syncthreads();

            #pragma unroll
            for (int dl = 0; dl < DCH; ++dl) {
                const float4 qv = *reinterpret_cast<const float4*>(
                    &Qs[dbase + dl][wrow]);           // wave-uniform broadcast
                const float qa[4] = {qv.x, qv.y, qv.z, qv.w};
                float kv[4];
                kv[0] = Ks[dl][tx];
                kv[1] = Ks[dl][tx + 64];
                kv[2] = Ks[dl][tx + 128];
                kv[3] = Ks[dl][tx + 192];
                #pragma unroll
                for (int rr = 0; rr < 4; ++rr)
                    #pragma unroll
                    for (int i = 0; i < 4; ++i)
                        acc[rr][i] = fmaf(qa[rr], kv[i], acc[rr][i]);
            }
        }

        // ---- epilogue: clamp-classified, bit-exact vs reference ----
        float rk[4];
        rk[0] = kk[c0 + tx];
        rk[1] = kk[c0 + tx + 64];
        rk[2] = kk[c0 + tx + 128];
        rk[3] = kk[c0 + tx + 192];

        #pragma unroll
        for (int rr = 0; rr < 4; ++rr) {
            #pragma unroll
            for (int i = 0; i < 4; ++i) {
                const float inner = acc[rr][i];
                const float dd2 = fmaxf(fabsf(rq[rr] * rk[i]), EPSV);
                float dist = 0.0f, sim = 0.0f, e = 1.0f;
                if (inner * inner > dd2 * 0.9999f) {  // rare: ratio may be >=1
                    const float ratio = fmaxf(fabsf(inner) / sqrtf(dd2), 1.0f);
                    dist = __logf(ratio + sqrtf(fmaf(ratio, ratio, -1.0f)));
                    sim  = dist * NEG_INV_T;
                    e    = __expf(sim);
                }
                __builtin_nontemporal_store(dist, pd[rr] + t * TN + 64 * i);
                __builtin_nontemporal_store(sim,  ps[rr] + t * TN + 64 * i);
                if (cs == 0 && t == 0 && i == 0 && tx == 0) sim0r[rr] = sim;
                s[rr] += e;
            }
        }
    }

    // ---- reduce S across the 64 lanes of each row ----
    #pragma unroll
    for (int rr = 0; rr < 4; ++rr) {
        float v = s[rr];
        #pragma unroll
        for (int mask = 32; mask > 0; mask >>= 1)
            v += __shfl_xor(v, mask, 64);
        s[rr] = v;
    }
    if (tx == 0) {
        #pragma unroll
        for (int rr = 0; rr < 4; ++rr) {
            const int row = row0 + wrow + rr;
            Spart[cs * NN + row] = s[rr];
            if (cs == 0) sim0part[row] = sim0r[rr];
        }
    }
}

// ---------------------------------------------------------------------------
// Kernel 4: loss = sum_i(-sim0_i + log(sum_{cs} Spart[cs][i])) / N.
// ---------------------------------------------------------------------------
__global__ __launch_bounds__(256) void uhg_finalize(
    const float* __restrict__ Spart, const float* __restrict__ sim0part,
    float* __restrict__ out)
{
    __shared__ float red[256];
    const int tid = threadIdx.x;
    float a = 0.0f;
    for (int r = tid; r < NN; r += 256) {
        float S = 0.0f;
        #pragma unroll
        for (int q = 0; q < 8; ++q) S += Spart[q * NN + r];
        a += -sim0part[r] + logf(S);
    }
    red[tid] = a;
    __syncthreads();
    for (int off = 128; off > 0; off >>= 1) {
        if (tid < off) red[tid] += red[tid + off];
        __syncthreads();
    }
    if (tid == 0) out[0] = red[0] / (float)NN;
}

// ---------------------------------------------------------------------------
extern "C" void kernel_launch(void* const* d_in, const int* in_sizes, int n_in,
                              void* d_out, int out_size, void* d_ws, size_t ws_size,
                              hipStream_t stream)
{
    const float* Q = (const float*)d_in[0];
    const float* K = (const float*)d_in[1];
    // d_in[2] (positive_indices) cancels analytically -> unused.

    float* out      = (float*)d_out;
    float* out_sims = out + 1;
    float* out_dist = out + 1 + (size_t)NN * NN;

    float* w        = (float*)d_ws;       // ~2.5MB of ws used
    float* Kt       = w;                  // 64*8192 = 524288
    float* qq       = w + 524288;         // 8192
    float* kk       = w + 532480;         // 8192
    float* Spart    = w + 540672;         // 8*8192 = 65536
    float* sim0part = w + 606208;         // 8192

    uhg_transpose_negate<<<NN / 64, 256, 0, stream>>>(K, Kt);
    uhg_qqkk<<<2 * NN / 256, 256, 0, stream>>>(Q, K, qq, kk);
    uhg_main<<<4096, 256, 0, stream>>>(Q, Kt, qq, kk, out_sims, out_dist,
                                       Spart, sim0part);
    uhg_finalize<<<1, 256, 0, stream>>>(Spart, sim0part, out);
}

// Round 7
// 655.603 us; speedup vs baseline: 25.4847x; 25.4847x over previous
//
#include <hip/hip_runtime.h>
#include <hip/hip_bf16.h>
#include <math.h>

// UHG InfoNCE: fused distance/similarity matrix + streaming row-logsumexp.
// N=8192, D=64 fp32. Mandatory writes ~537MB -> ~86us floor.
// r4: bit-exact, main ~300us (2 blocks/CU). r5: grid bug (half cols). r6:
// passed bit-exact but 16.3ms — __launch_bounds__(256,4) forced VGPR=64 ->
// catastrophic scratch spills (FETCH 38.5GB, VALUBusy 0.9%).
// r7: NO min-wave bound (let allocator breathe), per-tile epilogue address
// calc (fewer live regs), double-buffered 16-dim K chunks (one barrier per
// chunk, stage-next-then-compute), LDS 38.4KB -> 4 blocks/CU.
//
// Analytic simplifications (exact in fp32, proven absmax=0.0 in r4/r6):
//  1. pos_sim cancels: per_row = -sims[i,0] + logsumexp_j(sims[i,j]).
//  2. max(ratio, 1.0+1e-9) == max(ratio, 1.0f) in fp32; ratio<1 for ~all
//     pairs -> dist=0, sim=0 exactly. Classify by inner^2 > 0.9999*denom2;
//     borderline lanes take the exact div/clamp path.
//  3. Row max is exactly 0 -> accumulate S = sum(exp(sim)) with m=0 fixed.

#define NN 8192
#define DD 64

static constexpr float EPSV      = 1e-9f;
static constexpr float NEG_INV_T = -1.0f / 0.07f;

typedef const __attribute__((address_space(1))) unsigned int* gas_u32p;
typedef __attribute__((address_space(3))) unsigned int* las_u32p;

__device__ __forceinline__ void load_lds16(const void* g, void* l) {
    __builtin_amdgcn_global_load_lds((gas_u32p)g, (las_u32p)l, 16, 0, 0);
}

// ---------------------------------------------------------------------------
// Kernel 1: Kt[d][j] = K[j][d], d==63 (timelike) negated.
// ---------------------------------------------------------------------------
__global__ __launch_bounds__(256) void uhg_transpose_negate(
    const float* __restrict__ K, float* __restrict__ Kt)
{
    __shared__ float T[64][65];
    const int tid = threadIdx.x;
    const int j0  = blockIdx.x * 64;
    {
        const int j = tid >> 2;
        const int c = (tid & 3) * 16;
        const float* src = K + (size_t)(j0 + j) * DD + c;
        #pragma unroll
        for (int u = 0; u < 4; ++u) {
            const float4 v = *reinterpret_cast<const float4*>(src + 4 * u);
            T[j][c + 4*u + 0] = v.x;
            T[j][c + 4*u + 1] = v.y;
            T[j][c + 4*u + 2] = v.z;
            T[j][c + 4*u + 3] = v.w;
        }
    }
    __syncthreads();
    {
        const int d = tid >> 2;
        const int c = (tid & 3) * 16;
        const float sgn = (d == 63) ? -1.0f : 1.0f;
        float* dst = Kt + (size_t)d * NN + j0 + c;
        #pragma unroll
        for (int u = 0; u < 4; ++u) {
            float4 v;
            v.x = sgn * T[c + 4*u + 0][d];
            v.y = sgn * T[c + 4*u + 1][d];
            v.z = sgn * T[c + 4*u + 2][d];
            v.w = sgn * T[c + 4*u + 3][d];
            *reinterpret_cast<float4*>(dst + 4 * u) = v;
        }
    }
}

// ---------------------------------------------------------------------------
// Kernel 2: Minkowski self-inner products qq[i], kk[j].
// ---------------------------------------------------------------------------
__global__ __launch_bounds__(256) void uhg_qqkk(
    const float* __restrict__ Q, const float* __restrict__ K,
    float* __restrict__ qq, float* __restrict__ kk)
{
    const int i = blockIdx.x * 256 + threadIdx.x;
    const bool isQ = (i < NN);
    const int r = isQ ? i : (i - NN);
    const float* src = (isQ ? Q : K) + (size_t)r * DD;
    float acc = 0.0f;
    #pragma unroll
    for (int c = 0; c < 15; ++c) {
        const float4 v = *reinterpret_cast<const float4*>(src + 4 * c);
        acc += v.x*v.x + v.y*v.y + v.z*v.z + v.w*v.w;
    }
    const float4 v = *reinterpret_cast<const float4*>(src + 60);
    acc += v.x*v.x + v.y*v.y + v.z*v.z;
    acc -= v.w*v.w;
    (isQ ? qq : kk)[r] = acc;
}

// ---------------------------------------------------------------------------
// Kernel 3: main fused kernel.
// Grid 4096 x 256 thr. Block (rblk, cs) owns rows [16*rblk,+16) x cols
// [1024*cs,+1024), cs in 0..7. 16 chunk-steps (4 tiles x 4 chunks of 16
// dims), double-buffered: stage step s+1, compute step s, one barrier/step.
// Thread: 4 rows x 4 strided cols. Bit-exact epilogue (r4/r6-verified).
// ---------------------------------------------------------------------------
__global__ __launch_bounds__(256) void uhg_main(
    const float* __restrict__ Q, const float* __restrict__ Kt,
    const float* __restrict__ qq, const float* __restrict__ kk,
    float* __restrict__ out_sims, float* __restrict__ out_dist,
    float* __restrict__ Spart, float* __restrict__ sim0part)
{
    constexpr int TM  = 16;    // rows per block
    constexpr int CB  = 1024;  // cols per block
    constexpr int TN  = 256;   // cols per tile
    constexpr int DCH = 16;    // dims per K chunk
    constexpr int NSTEP = (CB / TN) * (DD / DCH);   // 16 chunk-steps

    __shared__ float Qs[DD][20];         // dim-major Q tile (pad 20)
    __shared__ float Ks[2][DCH][260];    // double-buffered K chunk (pad 260)

    const int tid   = threadIdx.x;
    const int tx    = tid & 63;
    const int ty    = tid >> 6;          // wave id (uniform)
    const int cs    = blockIdx.x & 7;    // column slice (8 x 1024 = full N)
    const int row0  = (blockIdx.x >> 3) * TM;
    const int cbase = cs * CB;
    const int wrow  = 4 * ty;

    // ---- stage Q tile (once): 16 rows x 64 dims, dim-major ----
    {
        const int r  = tid >> 4;         // 0..15
        const int dc = (tid & 15) * 4;
        const float4 v = *reinterpret_cast<const float4*>(
            Q + (size_t)(row0 + r) * DD + dc);
        Qs[dc + 0][r] = v.x;
        Qs[dc + 1][r] = v.y;
        Qs[dc + 2][r] = v.z;
        Qs[dc + 3][r] = v.w;
    }

    // ---- prologue: stage chunk-step 0 into buffer 0 ----
    {
        const int j = 4 * ty;            // wave stages rows j..j+3 (1KB each)
        #pragma unroll
        for (int u = 0; u < 4; ++u)
            load_lds16(Kt + (size_t)(j + u) * NN + cbase + 4 * tx,
                       &Ks[0][j + u][0]);
    }

    const float4 rq4 = *reinterpret_cast<const float4*>(qq + row0 + wrow);
    const float rq[4] = {rq4.x, rq4.y, rq4.z, rq4.w};

    float s[4]     = {0, 0, 0, 0};       // S = sum(exp(sim)), m fixed at 0
    float sim0r[4] = {0, 0, 0, 0};
    float acc[4][4] = {};

    __syncthreads();                     // Qs ready + step-0 staging landed

    for (int step = 0; step < NSTEP; ++step) {
        const int t     = step >> 2;
        const int ch    = step & 3;
        const int cur   = step & 1;
        const int dbase = ch * DCH;

        // ---- stage next chunk-step into the other buffer ----
        if (step + 1 < NSTEP) {
            const int tn     = (step + 1) >> 2;
            const int dbn    = ((step + 1) & 3) * DCH;
            const int c0n    = cbase + tn * TN;
            const int j      = 4 * ty;
            #pragma unroll
            for (int u = 0; u < 4; ++u)
                load_lds16(Kt + (size_t)(dbn + j + u) * NN + c0n + 4 * tx,
                           &Ks[cur ^ 1][j + u][0]);
        }

        // ---- compute current chunk: 16 dims x (4 rows x 4 cols) ----
        #pragma unroll
        for (int dl = 0; dl < DCH; ++dl) {
            const float4 qv = *reinterpret_cast<const float4*>(
                &Qs[dbase + dl][wrow]);              // wave-uniform broadcast
            const float qa[4] = {qv.x, qv.y, qv.z, qv.w};
            float kv[4];
            kv[0] = Ks[cur][dl][tx];
            kv[1] = Ks[cur][dl][tx + 64];
            kv[2] = Ks[cur][dl][tx + 128];
            kv[3] = Ks[cur][dl][tx + 192];
            #pragma unroll
            for (int rr = 0; rr < 4; ++rr)
                #pragma unroll
                for (int i = 0; i < 4; ++i)
                    acc[rr][i] = fmaf(qa[rr], kv[i], acc[rr][i]);
        }

        // ---- tile epilogue after its 4th chunk ----
        if (ch == 3) {
            const int c0 = cbase + t * TN;
            float rk[4];
            rk[0] = kk[c0 + tx];
            rk[1] = kk[c0 + tx + 64];
            rk[2] = kk[c0 + tx + 128];
            rk[3] = kk[c0 + tx + 192];

            #pragma unroll
            for (int rr = 0; rr < 4; ++rr) {
                const size_t rowoff =
                    (size_t)(row0 + wrow + rr) * NN + c0 + tx;
                float* psr = out_sims + rowoff;
                float* pdr = out_dist + rowoff;
                #pragma unroll
                for (int i = 0; i < 4; ++i) {
                    const float inner = acc[rr][i];
                    const float dd2 = fmaxf(fabsf(rq[rr] * rk[i]), EPSV);
                    float dist = 0.0f, sim = 0.0f, e = 1.0f;
                    if (inner * inner > dd2 * 0.9999f) {  // rare slow path
                        const float ratio =
                            fmaxf(fabsf(inner) / sqrtf(dd2), 1.0f);
                        dist = __logf(ratio + sqrtf(fmaf(ratio, ratio, -1.0f)));
                        sim  = dist * NEG_INV_T;
                        e    = __expf(sim);
                    }
                    __builtin_nontemporal_store(dist, pdr + 64 * i);
                    __builtin_nontemporal_store(sim,  psr + 64 * i);
                    if (cs == 0 && t == 0 && i == 0 && tx == 0)
                        sim0r[rr] = sim;
                    s[rr] += e;
                    acc[rr][i] = 0.0f;            // reset for next tile
                }
            }
        }

        __syncthreads();   // drains staging vmcnt + protects Ks buffers
    }

    // ---- reduce S across the 64 lanes of each row ----
    #pragma unroll
    for (int rr = 0; rr < 4; ++rr) {
        float v = s[rr];
        #pragma unroll
        for (int mask = 32; mask > 0; mask >>= 1)
            v += __shfl_xor(v, mask, 64);
        s[rr] = v;
    }
    if (tx == 0) {
        #pragma unroll
        for (int rr = 0; rr < 4; ++rr) {
            const int row = row0 + wrow + rr;
            Spart[cs * NN + row] = s[rr];
            if (cs == 0) sim0part[row] = sim0r[rr];
        }
    }
}

// ---------------------------------------------------------------------------
// Kernel 4: loss = sum_i(-sim0_i + log(sum_{cs} Spart[cs][i])) / N.
// ---------------------------------------------------------------------------
__global__ __launch_bounds__(256) void uhg_finalize(
    const float* __restrict__ Spart, const float* __restrict__ sim0part,
    float* __restrict__ out)
{
    __shared__ float red[256];
    const int tid = threadIdx.x;
    float a = 0.0f;
    for (int r = tid; r < NN; r += 256) {
        float S = 0.0f;
        #pragma unroll
        for (int q = 0; q < 8; ++q) S += Spart[q * NN + r];
        a += -sim0part[r] + logf(S);
    }
    red[tid] = a;
    __syncthreads();
    for (int off = 128; off > 0; off >>= 1) {
        if (tid < off) red[tid] += red[tid + off];
        __syncthreads();
    }
    if (tid == 0) out[0] = red[0] / (float)NN;
}

// ---------------------------------------------------------------------------
extern "C" void kernel_launch(void* const* d_in, const int* in_sizes, int n_in,
                              void* d_out, int out_size, void* d_ws, size_t ws_size,
                              hipStream_t stream)
{
    const float* Q = (const float*)d_in[0];
    const float* K = (const float*)d_in[1];
    // d_in[2] (positive_indices) cancels analytically -> unused.

    float* out      = (float*)d_out;
    float* out_sims = out + 1;
    float* out_dist = out + 1 + (size_t)NN * NN;

    float* w        = (float*)d_ws;       // ~2.5MB of ws used
    float* Kt       = w;                  // 64*8192 = 524288
    float* qq       = w + 524288;         // 8192
    float* kk       = w + 532480;         // 8192
    float* Spart    = w + 540672;         // 8*8192 = 65536
    float* sim0part = w + 606208;         // 8192

    uhg_transpose_negate<<<NN / 64, 256, 0, stream>>>(K, Kt);
    uhg_qqkk<<<2 * NN / 256, 256, 0, stream>>>(Q, K, qq, kk);
    uhg_main<<<4096, 256, 0, stream>>>(Q, Kt, qq, kk, out_sims, out_dist,
                                       Spart, sim0part);
    uhg_finalize<<<1, 256, 0, stream>>>(Spart, sim0part, out);
}